// Round 1
// baseline (950.295 us; speedup 1.0000x reference)
//
#include <hip/hip_runtime.h>
#include <stdint.h>

#define D_MODEL 1024
#define EXP_D   4096
#define NE      8
#define NTOK    8192
#define BMT     128
#define MAX_TILES 136
#define NS_MAX  17408   // MAX_TILES*128

typedef __attribute__((ext_vector_type(8))) short short8;
typedef __attribute__((ext_vector_type(4))) float f32x4;
typedef __attribute__((ext_vector_type(4))) unsigned short us4;

// ---- workspace layout (bytes) ----
#define WS_COUNTS    0          // int[8]
#define WS_CURSORS   32         // int[8]
#define WS_PADOFF    64         // int[16]
#define WS_META      128        // int[32], meta[0]=ntiles
#define WS_TILE_E    256        // int[256]
#define WS_PP        4096       // float[2048*8]
#define WS_TOP_E     69632      // int[16384]
#define WS_TOP_W     135168     // float[16384]
#define WS_SLOT_TOK  200704     // int[17408]
#define WS_SLOT_W    270336     // float[17408]
#define WS_TOK_SLOT  339968     // int[16384]
#define WS_XG        405504     // bf16 [17408][1024]
#define WS_HB        36057088   // bf16 [17408][4096]
#define WS_YB        178663424  // bf16 [17408][1024]  (ends at 214,315,008)

__device__ __forceinline__ unsigned short f2bf(float f){
  __bf16 h = (__bf16)f;
  return __builtin_bit_cast(unsigned short, h);
}
__device__ __forceinline__ float bf2f(unsigned short u){
  unsigned int v = ((unsigned int)u) << 16;
  return __builtin_bit_cast(float, v);
}
__device__ __forceinline__ void gl_lds16(const void* g, void* l){
  __builtin_amdgcn_global_load_lds((const __attribute__((address_space(1))) unsigned int*)g,
                                   (__attribute__((address_space(3))) unsigned int*)l,
                                   16, 0, 0);
}

// ---------------- init: zero header, slot_token=-1, slot_w=0 ----------------
__global__ void init_kernel(int* __restrict__ hdr, int* __restrict__ slot_tok,
                            float* __restrict__ slot_w){
  const int i = blockIdx.x*256 + threadIdx.x;
  if (blockIdx.x == 0 && threadIdx.x < 64) hdr[threadIdx.x] = 0;
  if (i < NS_MAX){ slot_tok[i] = -1; slot_w[i] = 0.f; }
}

// ---------------- router: one wave per token ----------------
__global__ __launch_bounds__(256) void router_kernel(
    const float* __restrict__ x, const float* __restrict__ Wr,
    const float* __restrict__ br,
    int* __restrict__ counts, int* __restrict__ top_e, float* __restrict__ top_w,
    float* __restrict__ pp)
{
  __shared__ float WrS[NE*D_MODEL];
  __shared__ float wprob[4][NE];
  const int tid = threadIdx.x;
#pragma unroll
  for (int i=0;i<8;++i){
    int j = (tid + i*256)*4;
    *(float4*)&WrS[j] = *(const float4*)&Wr[j];
  }
  __syncthreads();
  const int w = tid>>6, lane = tid&63;
  const int t = blockIdx.x*4 + w;
  const float* xt = x + (size_t)t*D_MODEL;
  float accv[8] = {0,0,0,0,0,0,0,0};
#pragma unroll
  for (int i=0;i<4;++i){
    const int k = i*256 + lane*4;
    const float4 xv = *(const float4*)&xt[k];
#pragma unroll
    for (int e=0;e<8;++e){
      const float4 wv = *(const float4*)&WrS[e*D_MODEL + k];
      accv[e] += xv.x*wv.x + xv.y*wv.y + xv.z*wv.z + xv.w*wv.w;
    }
  }
#pragma unroll
  for (int m=32;m>0;m>>=1){
#pragma unroll
    for (int e=0;e<8;++e) accv[e] += __shfl_xor(accv[e], m, 64);
  }
  if (lane==0){
    float lg[8];
#pragma unroll
    for (int e=0;e<8;++e) lg[e] = accv[e] + br[e];
    float mx = lg[0];
#pragma unroll
    for (int e=1;e<8;++e) mx = fmaxf(mx, lg[e]);
    float p[8]; float s=0.f;
#pragma unroll
    for (int e=0;e<8;++e){ p[e] = __expf(lg[e]-mx); s += p[e]; }
    const float inv = 1.f/s;
#pragma unroll
    for (int e=0;e<8;++e){ p[e] *= inv; wprob[w][e] = p[e]; }
    int i1=0; float p1v=p[0];
#pragma unroll
    for (int e=1;e<8;++e) if (p[e] > p1v){ p1v=p[e]; i1=e; }
    int i2=-1; float p2v=-1.f;
#pragma unroll
    for (int e=0;e<8;++e) if (e!=i1 && p[e] > p2v){ p2v=p[e]; i2=e; }
    const float rn = 1.f/(p1v+p2v);
    top_e[2*t]   = i1; top_w[2*t]   = p1v*rn;
    top_e[2*t+1] = i2; top_w[2*t+1] = p2v*rn;
    atomicAdd(&counts[i1],1);
    atomicAdd(&counts[i2],1);
  }
  __syncthreads();
  if (tid<8){
    pp[blockIdx.x*8+tid] = wprob[0][tid]+wprob[1][tid]+wprob[2][tid]+wprob[3][tid];
  }
}

// ---------------- prefix: tile table + aux loss ----------------
__global__ void prefix_kernel(int* __restrict__ wsI, const float* __restrict__ pp,
                              float* __restrict__ aux_out){
  const int tid = threadIdx.x;
  __shared__ float dev2[8];
  if (tid==0){
    int* counts = wsI + 0;
    int* padoff = wsI + 16;
    int* meta   = wsI + 32;
    int* tileE  = wsI + 64;
    int nt = 0;
    for (int e=0;e<NE;++e){
      padoff[e] = nt*BMT;
      int tiles = (counts[e] + BMT - 1) >> 7;
      for (int i=0;i<tiles;++i) tileE[nt++] = e;
    }
    meta[0] = nt;
  }
  if (tid<8){
    float s=0.f;
    for (int b=0;b<NTOK/4;++b) s += pp[b*8+tid];
    float d = s*(1.f/(float)NTOK) - 0.125f;
    dev2[tid] = d*d;
  }
  __syncthreads();
  if (tid==0){
    float a=0.f;
#pragma unroll
    for (int e=0;e<8;++e) a += dev2[e];
    aux_out[0] = a;
  }
}

// ---------------- scatter tokens to slots ----------------
__global__ void scatter_kernel(const int* __restrict__ top_e, const float* __restrict__ top_w,
                               int* __restrict__ cursors, const int* __restrict__ padoff,
                               int* __restrict__ slot_tok, float* __restrict__ slot_w,
                               int* __restrict__ tok_slot)
{
  const int t = blockIdx.x*256 + threadIdx.x;
  if (t >= NTOK) return;
#pragma unroll
  for (int k=0;k<2;++k){
    const int e = top_e[2*t+k];
    const int pos = atomicAdd(&cursors[e], 1);
    const int s = padoff[e] + pos;
    slot_tok[s] = t;
    slot_w[s] = top_w[2*t+k];
    tok_slot[2*t+k] = s;
  }
}

// ---------------- gather x rows -> bf16 slot rows ----------------
__global__ __launch_bounds__(256) void gather_kernel(
    const float* __restrict__ x, const int* __restrict__ slot_tok,
    unsigned short* __restrict__ Xg)
{
  const int s = blockIdx.x;
  const int tid = threadIdx.x;
  const int tok = slot_tok[s];
  us4 o;
  if (tok < 0){
    o[0]=0;o[1]=0;o[2]=0;o[3]=0;
  } else {
    const float4 v = *(const float4*)&x[(size_t)tok*D_MODEL + tid*4];
    o[0]=f2bf(v.x); o[1]=f2bf(v.y); o[2]=f2bf(v.z); o[3]=f2bf(v.w);
  }
  *(us4*)&Xg[(size_t)s*D_MODEL + tid*4] = o;
}

// ---------------- grouped GEMM (m97-style 128x128 tile, BK=32) ----------------
// C[row][n] = sum_k A[row][k] * W[e][n][k]  (+bias; GEMM1: relu; GEMM2: *slot_w)
template<int KT, int NT, bool G2>
__global__ __launch_bounds__(256) void moe_gemm(
    const unsigned short* __restrict__ A,
    const float* __restrict__ W,
    const float* __restrict__ bias,
    unsigned short* __restrict__ Cout,
    const int* __restrict__ tileE,
    const int* __restrict__ meta,
    const float* __restrict__ slotw)
{
  if ((int)blockIdx.y >= meta[0]) return;
  __shared__ unsigned short Alds[128*32];
  __shared__ unsigned short Blds[128*32];
  const int tid  = threadIdx.x;
  const int e    = tileE[blockIdx.y];
  const int m0   = blockIdx.y * BMT;
  const int n0   = blockIdx.x * 128;
  const float* We = W + (size_t)e*NT*KT;
  const unsigned short* Ap = A + (size_t)(m0 + (tid>>2))*KT + (tid&3)*8;
  const float* Bp0 = We + (size_t)(n0 + (tid>>2))*KT + (tid&3)*8;
  const float* Bp1 = Bp0 + (size_t)64*KT;
  const int lane = tid & 63;
  const int wv   = tid >> 6;
  const int wm   = wv >> 1, wn = wv & 1;
  const int r16  = lane & 15, kg = lane >> 4;
  const int aA = (wm*64 + r16)*32 + kg*8;
  const int aB = (wn*64 + r16)*32 + kg*8;
  f32x4 acc[4][4];
#pragma unroll
  for (int i=0;i<4;++i)
#pragma unroll
    for (int j=0;j<4;++j) acc[i][j] = (f32x4){0.f,0.f,0.f,0.f};

  for (int kt=0; kt<KT/32; ++kt){
    const int kb = kt*32;
    // A tile: 128x32 bf16 via async global->LDS (2 x 16B per thread)
    gl_lds16(Ap + kb,           &Alds[tid*8]);
    gl_lds16(Ap + kb + 64*KT,   &Alds[2048 + tid*8]);
    // B tile: 128x32, fp32 source converted to bf16 in-register
    const float4 f0 = *(const float4*)(Bp0 + kb);
    const float4 f1 = *(const float4*)(Bp0 + kb + 4);
    const float4 f2 = *(const float4*)(Bp1 + kb);
    const float4 f3 = *(const float4*)(Bp1 + kb + 4);
    short8 v0, v1;
    v0[0]=(short)f2bf(f0.x); v0[1]=(short)f2bf(f0.y); v0[2]=(short)f2bf(f0.z); v0[3]=(short)f2bf(f0.w);
    v0[4]=(short)f2bf(f1.x); v0[5]=(short)f2bf(f1.y); v0[6]=(short)f2bf(f1.z); v0[7]=(short)f2bf(f1.w);
    v1[0]=(short)f2bf(f2.x); v1[1]=(short)f2bf(f2.y); v1[2]=(short)f2bf(f2.z); v1[3]=(short)f2bf(f2.w);
    v1[4]=(short)f2bf(f3.x); v1[5]=(short)f2bf(f3.y); v1[6]=(short)f2bf(f3.z); v1[7]=(short)f2bf(f3.w);
    *(short8*)&Blds[tid*8]        = v0;
    *(short8*)&Blds[2048 + tid*8] = v1;
    __syncthreads();
    short8 af[4], bfv[4];
#pragma unroll
    for (int fm=0;fm<4;++fm) af[fm]  = *(const short8*)&Alds[aA + fm*512];
#pragma unroll
    for (int fn=0;fn<4;++fn) bfv[fn] = *(const short8*)&Blds[aB + fn*512];
#pragma unroll
    for (int fm=0;fm<4;++fm)
#pragma unroll
      for (int fn=0;fn<4;++fn)
        acc[fm][fn] = __builtin_amdgcn_mfma_f32_16x16x32_bf16(af[fm], bfv[fn], acc[fm][fn], 0,0,0);
    __syncthreads();
  }

  float bvv[4];
#pragma unroll
  for (int fn=0;fn<4;++fn) bvv[fn] = bias[(size_t)e*NT + n0 + wn*64 + fn*16 + r16];
#pragma unroll
  for (int fm=0;fm<4;++fm){
    const int rowb = m0 + wm*64 + fm*16 + kg*4;
    float wg0=0.f,wg1=0.f,wg2=0.f,wg3=0.f;
    if (G2){ wg0=slotw[rowb]; wg1=slotw[rowb+1]; wg2=slotw[rowb+2]; wg3=slotw[rowb+3]; }
#pragma unroll
    for (int fn=0;fn<4;++fn){
      const int col = n0 + wn*64 + fn*16 + r16;
      unsigned short* cp = Cout + (size_t)rowb*NT + col;
      float q0 = acc[fm][fn][0] + bvv[fn];
      float q1 = acc[fm][fn][1] + bvv[fn];
      float q2 = acc[fm][fn][2] + bvv[fn];
      float q3 = acc[fm][fn][3] + bvv[fn];
      if (!G2){
        q0=fmaxf(q0,0.f); q1=fmaxf(q1,0.f); q2=fmaxf(q2,0.f); q3=fmaxf(q3,0.f);
      } else {
        q0*=wg0; q1*=wg1; q2*=wg2; q3*=wg3;
      }
      cp[0]            = f2bf(q0);
      cp[(size_t)NT]   = f2bf(q1);
      cp[(size_t)2*NT] = f2bf(q2);
      cp[(size_t)3*NT] = f2bf(q3);
    }
  }
}

// ---------------- combine: out[t] = Y[slot0] + Y[slot1] ----------------
__global__ __launch_bounds__(256) void combine_kernel(
    const unsigned short* __restrict__ Yb, const int* __restrict__ tok_slot,
    float* __restrict__ out)
{
  const int t = blockIdx.x;
  const int tid = threadIdx.x;
  const int s0 = tok_slot[2*t], s1 = tok_slot[2*t+1];
  const us4 a = *(const us4*)&Yb[(size_t)s0*D_MODEL + tid*4];
  const us4 b = *(const us4*)&Yb[(size_t)s1*D_MODEL + tid*4];
  float4 o;
  o.x = bf2f(a[0]) + bf2f(b[0]);
  o.y = bf2f(a[1]) + bf2f(b[1]);
  o.z = bf2f(a[2]) + bf2f(b[2]);
  o.w = bf2f(a[3]) + bf2f(b[3]);
  *(float4*)&out[(size_t)t*D_MODEL + tid*4] = o;
}

extern "C" void kernel_launch(void* const* d_in, const int* in_sizes, int n_in,
                              void* d_out, int out_size, void* d_ws, size_t ws_size,
                              hipStream_t stream)
{
  const float* x  = (const float*)d_in[0];
  const float* Wr = (const float*)d_in[1];
  const float* br = (const float*)d_in[2];
  const float* W1 = (const float*)d_in[3];
  const float* b1 = (const float*)d_in[4];
  const float* W2 = (const float*)d_in[5];
  const float* b2 = (const float*)d_in[6];
  float* out = (float*)d_out;
  char* ws = (char*)d_ws;

  int*   counts  = (int*)(ws + WS_COUNTS);
  int*   cursors = (int*)(ws + WS_CURSORS);
  int*   padoff  = (int*)(ws + WS_PADOFF);
  int*   meta    = (int*)(ws + WS_META);
  int*   tileE   = (int*)(ws + WS_TILE_E);
  float* pp      = (float*)(ws + WS_PP);
  int*   top_e   = (int*)(ws + WS_TOP_E);
  float* top_w   = (float*)(ws + WS_TOP_W);
  int*   slot_tok= (int*)(ws + WS_SLOT_TOK);
  float* slot_w  = (float*)(ws + WS_SLOT_W);
  int*   tok_slot= (int*)(ws + WS_TOK_SLOT);
  unsigned short* Xg = (unsigned short*)(ws + WS_XG);
  unsigned short* Hb = (unsigned short*)(ws + WS_HB);
  unsigned short* Yb = (unsigned short*)(ws + WS_YB);

  init_kernel<<<dim3(68), dim3(256), 0, stream>>>((int*)ws, slot_tok, slot_w);
  router_kernel<<<dim3(NTOK/4), dim3(256), 0, stream>>>(x, Wr, br, counts, top_e, top_w, pp);
  prefix_kernel<<<dim3(1), dim3(256), 0, stream>>>((int*)ws, pp, out + (size_t)NTOK*D_MODEL);
  scatter_kernel<<<dim3(NTOK/256), dim3(256), 0, stream>>>(top_e, top_w, cursors, padoff,
                                                           slot_tok, slot_w, tok_slot);
  gather_kernel<<<dim3(NS_MAX), dim3(256), 0, stream>>>(x, slot_tok, Xg);
  moe_gemm<D_MODEL, EXP_D, false><<<dim3(EXP_D/128, MAX_TILES), dim3(256), 0, stream>>>(
      Xg, W1, b1, Hb, tileE, meta, slot_w);
  moe_gemm<EXP_D, D_MODEL, true><<<dim3(D_MODEL/128, MAX_TILES), dim3(256), 0, stream>>>(
      Hb, W2, b2, Yb, tileE, meta, slot_w);
  combine_kernel<<<dim3(NTOK), dim3(256), 0, stream>>>(Yb, tok_slot, out);
}

// Round 2
// 837.418 us; speedup vs baseline: 1.1348x; 1.1348x over previous
//
#include <hip/hip_runtime.h>
#include <stdint.h>

#define D_MODEL 1024
#define EXP_D   4096
#define NE      8
#define NTOK    8192
#define BMT     128
#define MAX_TILES 136
#define NS_MAX  17408   // MAX_TILES*128

typedef __attribute__((ext_vector_type(8))) short short8;
typedef __attribute__((ext_vector_type(4))) float f32x4;
typedef __attribute__((ext_vector_type(4))) unsigned short us4;

// ---- workspace layout (bytes) ----
#define WS_COUNTS    0          // int[8]
#define WS_CURSORS   32         // int[8]
#define WS_PADOFF    64         // int[16]
#define WS_META      128        // int[32], meta[0]=ntiles
#define WS_TILE_E    256        // int[256]
#define WS_PP        4096       // float[2048*8]
#define WS_TOP_E     69632      // int[16384]
#define WS_TOP_W     135168     // float[16384]
#define WS_SLOT_TOK  200704     // int[17408]
#define WS_SLOT_W    270336     // float[17408]
#define WS_TOK_SLOT  339968     // int[16384]
#define WS_XG        405504     // bf16 [17408][1024]  (new mode: Yb aliases this)
#define WS_HB        36057088   // bf16 [17408][4096]
#define WS_WB        178663424  // bf16 [8][4096][1024] weights (new mode), 67.1 MB -> ends 245,772,288
#define WS_YB_OLD    178663424  // bf16 [17408][1024]  (fallback mode)   -> ends 214,315,008
#define REQ_NEW      245772288ull
#define REQ_OLD      214315008ull

__device__ __forceinline__ unsigned short f2bf(float f){
  __bf16 h = (__bf16)f;
  return __builtin_bit_cast(unsigned short, h);
}
__device__ __forceinline__ float bf2f(unsigned short u){
  unsigned int v = ((unsigned int)u) << 16;
  return __builtin_bit_cast(float, v);
}
__device__ __forceinline__ void gl_lds16(const void* g, void* l){
  __builtin_amdgcn_global_load_lds((const __attribute__((address_space(1))) unsigned int*)g,
                                   (__attribute__((address_space(3))) unsigned int*)l,
                                   16, 0, 0);
}

// ---------------- init: zero header, slot_token=-1, slot_w=0 ----------------
__global__ void init_kernel(int* __restrict__ hdr, int* __restrict__ slot_tok,
                            float* __restrict__ slot_w){
  const int i = blockIdx.x*256 + threadIdx.x;
  if (blockIdx.x == 0 && threadIdx.x < 64) hdr[threadIdx.x] = 0;
  if (i < NS_MAX){ slot_tok[i] = -1; slot_w[i] = 0.f; }
}

// ---------------- weight fp32 -> bf16 convert (E*h*d elements) ----------------
__global__ __launch_bounds__(256) void cvt_kernel(const float* __restrict__ W,
                                                  unsigned short* __restrict__ Wb){
  const int n4 = NE*EXP_D*D_MODEL/4;
  for (int i = blockIdx.x*256 + threadIdx.x; i < n4; i += gridDim.x*256){
    const float4 v = *(const float4*)&W[(size_t)i*4];
    us4 o; o[0]=f2bf(v.x); o[1]=f2bf(v.y); o[2]=f2bf(v.z); o[3]=f2bf(v.w);
    *(us4*)&Wb[(size_t)i*4] = o;
  }
}

// ---------------- router: one wave per token ----------------
__global__ __launch_bounds__(256) void router_kernel(
    const float* __restrict__ x, const float* __restrict__ Wr,
    const float* __restrict__ br,
    int* __restrict__ counts, int* __restrict__ top_e, float* __restrict__ top_w,
    float* __restrict__ pp)
{
  __shared__ float WrS[NE*D_MODEL];
  __shared__ float wprob[4][NE];
  const int tid = threadIdx.x;
#pragma unroll
  for (int i=0;i<8;++i){
    int j = (tid + i*256)*4;
    *(float4*)&WrS[j] = *(const float4*)&Wr[j];
  }
  __syncthreads();
  const int w = tid>>6, lane = tid&63;
  const int t = blockIdx.x*4 + w;
  const float* xt = x + (size_t)t*D_MODEL;
  float accv[8] = {0,0,0,0,0,0,0,0};
#pragma unroll
  for (int i=0;i<4;++i){
    const int k = i*256 + lane*4;
    const float4 xv = *(const float4*)&xt[k];
#pragma unroll
    for (int e=0;e<8;++e){
      const float4 wv = *(const float4*)&WrS[e*D_MODEL + k];
      accv[e] += xv.x*wv.x + xv.y*wv.y + xv.z*wv.z + xv.w*wv.w;
    }
  }
#pragma unroll
  for (int m=32;m>0;m>>=1){
#pragma unroll
    for (int e=0;e<8;++e) accv[e] += __shfl_xor(accv[e], m, 64);
  }
  if (lane==0){
    float lg[8];
#pragma unroll
    for (int e=0;e<8;++e) lg[e] = accv[e] + br[e];
    float mx = lg[0];
#pragma unroll
    for (int e=1;e<8;++e) mx = fmaxf(mx, lg[e]);
    float p[8]; float s=0.f;
#pragma unroll
    for (int e=0;e<8;++e){ p[e] = __expf(lg[e]-mx); s += p[e]; }
    const float inv = 1.f/s;
#pragma unroll
    for (int e=0;e<8;++e){ p[e] *= inv; wprob[w][e] = p[e]; }
    int i1=0; float p1v=p[0];
#pragma unroll
    for (int e=1;e<8;++e) if (p[e] > p1v){ p1v=p[e]; i1=e; }
    int i2=-1; float p2v=-1.f;
#pragma unroll
    for (int e=0;e<8;++e) if (e!=i1 && p[e] > p2v){ p2v=p[e]; i2=e; }
    const float rn = 1.f/(p1v+p2v);
    top_e[2*t]   = i1; top_w[2*t]   = p1v*rn;
    top_e[2*t+1] = i2; top_w[2*t+1] = p2v*rn;
    atomicAdd(&counts[i1],1);
    atomicAdd(&counts[i2],1);
  }
  __syncthreads();
  if (tid<8){
    pp[blockIdx.x*8+tid] = wprob[0][tid]+wprob[1][tid]+wprob[2][tid]+wprob[3][tid];
  }
}

// ---------------- prefix: tile table + aux loss ----------------
__global__ void prefix_kernel(int* __restrict__ wsI, const float* __restrict__ pp,
                              float* __restrict__ aux_out){
  const int tid = threadIdx.x;
  __shared__ float dev2[8];
  if (tid==0){
    int* counts = wsI + 0;
    int* padoff = wsI + 16;
    int* meta   = wsI + 32;
    int* tileE  = wsI + 64;
    int nt = 0;
    for (int e=0;e<NE;++e){
      padoff[e] = nt*BMT;
      int tiles = (counts[e] + BMT - 1) >> 7;
      for (int i=0;i<tiles;++i) tileE[nt++] = e;
    }
    meta[0] = nt;
  }
  if (tid<8){
    float s=0.f;
    for (int b=0;b<NTOK/4;++b) s += pp[b*8+tid];
    float d = s*(1.f/(float)NTOK) - 0.125f;
    dev2[tid] = d*d;
  }
  __syncthreads();
  if (tid==0){
    float a=0.f;
#pragma unroll
    for (int e=0;e<8;++e) a += dev2[e];
    aux_out[0] = a;
  }
}

// ---------------- scatter tokens to slots ----------------
__global__ void scatter_kernel(const int* __restrict__ top_e, const float* __restrict__ top_w,
                               int* __restrict__ cursors, const int* __restrict__ padoff,
                               int* __restrict__ slot_tok, float* __restrict__ slot_w,
                               int* __restrict__ tok_slot)
{
  const int t = blockIdx.x*256 + threadIdx.x;
  if (t >= NTOK) return;
#pragma unroll
  for (int k=0;k<2;++k){
    const int e = top_e[2*t+k];
    const int pos = atomicAdd(&cursors[e], 1);
    const int s = padoff[e] + pos;
    slot_tok[s] = t;
    slot_w[s] = top_w[2*t+k];
    tok_slot[2*t+k] = s;
  }
}

// ---------------- gather x rows -> bf16 slot rows ----------------
__global__ __launch_bounds__(256) void gather_kernel(
    const float* __restrict__ x, const int* __restrict__ slot_tok,
    unsigned short* __restrict__ Xg)
{
  const int s = blockIdx.x;
  const int tid = threadIdx.x;
  const int tok = slot_tok[s];
  us4 o;
  if (tok < 0){
    o[0]=0;o[1]=0;o[2]=0;o[3]=0;
  } else {
    const float4 v = *(const float4*)&x[(size_t)tok*D_MODEL + tid*4];
    o[0]=f2bf(v.x); o[1]=f2bf(v.y); o[2]=f2bf(v.z); o[3]=f2bf(v.w);
  }
  *(us4*)&Xg[(size_t)s*D_MODEL + tid*4] = o;
}

// ---------------- grouped GEMM (128x128 tile, BK=32, XCD-chunk swizzle) ----------------
// C[row][n] = sum_k A[row][k] * W[e][n][k]  (+bias; GEMM1: relu; GEMM2: *slot_w)
template<int KT, int NT, bool G2, bool BBF16>
__global__ __launch_bounds__(256) void moe_gemm(
    const unsigned short* __restrict__ A,
    const float* __restrict__ Wf,
    const unsigned short* __restrict__ Wb,
    const float* __restrict__ bias,
    unsigned short* __restrict__ Cout,
    const int* __restrict__ tileE,
    const int* __restrict__ meta,
    const float* __restrict__ slotw)
{
  constexpr int NX = NT/128;
  constexpr int TOTAL = NX*MAX_TILES;
  constexpr int Q = TOTAL/8, R = TOTAL%8;
  // bijective XCD chunk swizzle: hardware round-robins blockIdx%8 across XCDs;
  // give each XCD a contiguous range of tile ids (N-fastest -> A-tile L2 reuse).
  const int lid = blockIdx.x;
  const int xc = lid & 7, jj = lid >> 3;
  const int t  = xc*Q + (xc < R ? xc : R) + jj;
  const int mtile = t / NX, ntile = t - mtile*NX;
  if (mtile >= meta[0]) return;

  __shared__ unsigned short Alds[128*32];
  __shared__ unsigned short Blds[128*32];
  const int tid  = threadIdx.x;
  const int e    = tileE[mtile];
  const int m0   = mtile * BMT;
  const int n0   = ntile * 128;
  const unsigned short* Ap = A + (size_t)(m0 + (tid>>2))*KT + (tid&3)*8;
  const unsigned short* Bpb = Wb + (size_t)e*NT*KT + (size_t)(n0 + (tid>>2))*KT + (tid&3)*8;
  const float* Bp0 = Wf + (size_t)e*NT*KT + (size_t)(n0 + (tid>>2))*KT + (tid&3)*8;
  const float* Bp1 = Bp0 + (size_t)64*KT;
  const int lane = tid & 63;
  const int wv   = tid >> 6;
  const int wm   = wv >> 1, wn = wv & 1;
  const int r16  = lane & 15, kg = lane >> 4;
  const int aA = (wm*64 + r16)*32 + kg*8;
  const int aB = (wn*64 + r16)*32 + kg*8;
  f32x4 acc[4][4];
#pragma unroll
  for (int i=0;i<4;++i)
#pragma unroll
    for (int j=0;j<4;++j) acc[i][j] = (f32x4){0.f,0.f,0.f,0.f};

  for (int kt=0; kt<KT/32; ++kt){
    const int kb = kt*32;
    gl_lds16(Ap + kb,           &Alds[tid*8]);
    gl_lds16(Ap + kb + 64*KT,   &Alds[2048 + tid*8]);
    if constexpr (BBF16){
      gl_lds16(Bpb + kb,          &Blds[tid*8]);
      gl_lds16(Bpb + kb + 64*KT,  &Blds[2048 + tid*8]);
    } else {
      const float4 f0 = *(const float4*)(Bp0 + kb);
      const float4 f1 = *(const float4*)(Bp0 + kb + 4);
      const float4 f2 = *(const float4*)(Bp1 + kb);
      const float4 f3 = *(const float4*)(Bp1 + kb + 4);
      short8 v0, v1;
      v0[0]=(short)f2bf(f0.x); v0[1]=(short)f2bf(f0.y); v0[2]=(short)f2bf(f0.z); v0[3]=(short)f2bf(f0.w);
      v0[4]=(short)f2bf(f1.x); v0[5]=(short)f2bf(f1.y); v0[6]=(short)f2bf(f1.z); v0[7]=(short)f2bf(f1.w);
      v1[0]=(short)f2bf(f2.x); v1[1]=(short)f2bf(f2.y); v1[2]=(short)f2bf(f2.z); v1[3]=(short)f2bf(f2.w);
      v1[4]=(short)f2bf(f3.x); v1[5]=(short)f2bf(f3.y); v1[6]=(short)f2bf(f3.z); v1[7]=(short)f2bf(f3.w);
      *(short8*)&Blds[tid*8]        = v0;
      *(short8*)&Blds[2048 + tid*8] = v1;
    }
    __syncthreads();
    short8 af[4], bfv[4];
#pragma unroll
    for (int fm=0;fm<4;++fm) af[fm]  = *(const short8*)&Alds[aA + fm*512];
#pragma unroll
    for (int fn=0;fn<4;++fn) bfv[fn] = *(const short8*)&Blds[aB + fn*512];
#pragma unroll
    for (int fm=0;fm<4;++fm)
#pragma unroll
      for (int fn=0;fn<4;++fn)
        acc[fm][fn] = __builtin_amdgcn_mfma_f32_16x16x32_bf16(af[fm], bfv[fn], acc[fm][fn], 0,0,0);
    __syncthreads();
  }

  float bvv[4];
#pragma unroll
  for (int fn=0;fn<4;++fn) bvv[fn] = bias[(size_t)e*NT + n0 + wn*64 + fn*16 + r16];
#pragma unroll
  for (int fm=0;fm<4;++fm){
    const int rowb = m0 + wm*64 + fm*16 + kg*4;
    float wg0=0.f,wg1=0.f,wg2=0.f,wg3=0.f;
    if (G2){ wg0=slotw[rowb]; wg1=slotw[rowb+1]; wg2=slotw[rowb+2]; wg3=slotw[rowb+3]; }
#pragma unroll
    for (int fn=0;fn<4;++fn){
      const int col = n0 + wn*64 + fn*16 + r16;
      unsigned short* cp = Cout + (size_t)rowb*NT + col;
      float q0 = acc[fm][fn][0] + bvv[fn];
      float q1 = acc[fm][fn][1] + bvv[fn];
      float q2 = acc[fm][fn][2] + bvv[fn];
      float q3 = acc[fm][fn][3] + bvv[fn];
      if (!G2){
        q0=fmaxf(q0,0.f); q1=fmaxf(q1,0.f); q2=fmaxf(q2,0.f); q3=fmaxf(q3,0.f);
      } else {
        q0*=wg0; q1*=wg1; q2*=wg2; q3*=wg3;
      }
      cp[0]            = f2bf(q0);
      cp[(size_t)NT]   = f2bf(q1);
      cp[(size_t)2*NT] = f2bf(q2);
      cp[(size_t)3*NT] = f2bf(q3);
    }
  }
}

// ---------------- combine: out[t] = Y[slot0] + Y[slot1] ----------------
__global__ __launch_bounds__(256) void combine_kernel(
    const unsigned short* __restrict__ Yb, const int* __restrict__ tok_slot,
    float* __restrict__ out)
{
  const int t = blockIdx.x;
  const int tid = threadIdx.x;
  const int s0 = tok_slot[2*t], s1 = tok_slot[2*t+1];
  const us4 a = *(const us4*)&Yb[(size_t)s0*D_MODEL + tid*4];
  const us4 b = *(const us4*)&Yb[(size_t)s1*D_MODEL + tid*4];
  float4 o;
  o.x = bf2f(a[0]) + bf2f(b[0]);
  o.y = bf2f(a[1]) + bf2f(b[1]);
  o.z = bf2f(a[2]) + bf2f(b[2]);
  o.w = bf2f(a[3]) + bf2f(b[3]);
  *(float4*)&out[(size_t)t*D_MODEL + tid*4] = o;
}

extern "C" void kernel_launch(void* const* d_in, const int* in_sizes, int n_in,
                              void* d_out, int out_size, void* d_ws, size_t ws_size,
                              hipStream_t stream)
{
  const float* x  = (const float*)d_in[0];
  const float* Wr = (const float*)d_in[1];
  const float* br = (const float*)d_in[2];
  const float* W1 = (const float*)d_in[3];
  const float* b1 = (const float*)d_in[4];
  const float* W2 = (const float*)d_in[5];
  const float* b2 = (const float*)d_in[6];
  float* out = (float*)d_out;
  char* ws = (char*)d_ws;

  const bool bigws = ws_size >= REQ_NEW;

  int*   counts  = (int*)(ws + WS_COUNTS);
  int*   cursors = (int*)(ws + WS_CURSORS);
  int*   padoff  = (int*)(ws + WS_PADOFF);
  int*   meta    = (int*)(ws + WS_META);
  int*   tileE   = (int*)(ws + WS_TILE_E);
  float* pp      = (float*)(ws + WS_PP);
  int*   top_e   = (int*)(ws + WS_TOP_E);
  float* top_w   = (float*)(ws + WS_TOP_W);
  int*   slot_tok= (int*)(ws + WS_SLOT_TOK);
  float* slot_w  = (float*)(ws + WS_SLOT_W);
  int*   tok_slot= (int*)(ws + WS_TOK_SLOT);
  unsigned short* Xg = (unsigned short*)(ws + WS_XG);
  unsigned short* Hb = (unsigned short*)(ws + WS_HB);
  unsigned short* Wb = (unsigned short*)(ws + WS_WB);
  unsigned short* Yb = bigws ? Xg : (unsigned short*)(ws + WS_YB_OLD);

  init_kernel<<<dim3(68), dim3(256), 0, stream>>>((int*)ws, slot_tok, slot_w);
  router_kernel<<<dim3(NTOK/4), dim3(256), 0, stream>>>(x, Wr, br, counts, top_e, top_w, pp);
  prefix_kernel<<<dim3(1), dim3(256), 0, stream>>>((int*)ws, pp, out + (size_t)NTOK*D_MODEL);
  scatter_kernel<<<dim3(NTOK/256), dim3(256), 0, stream>>>(top_e, top_w, cursors, padoff,
                                                           slot_tok, slot_w, tok_slot);
  gather_kernel<<<dim3(NS_MAX), dim3(256), 0, stream>>>(x, slot_tok, Xg);

  if (bigws){
    cvt_kernel<<<dim3(2048), dim3(256), 0, stream>>>(W1, Wb);
    moe_gemm<D_MODEL, EXP_D, false, true><<<dim3((EXP_D/128)*MAX_TILES), dim3(256), 0, stream>>>(
        Xg, nullptr, Wb, b1, Hb, tileE, meta, slot_w);
    cvt_kernel<<<dim3(2048), dim3(256), 0, stream>>>(W2, Wb);
    moe_gemm<EXP_D, D_MODEL, true, true><<<dim3((D_MODEL/128)*MAX_TILES), dim3(256), 0, stream>>>(
        Hb, nullptr, Wb, b2, Yb, tileE, meta, slot_w);
  } else {
    moe_gemm<D_MODEL, EXP_D, false, false><<<dim3((EXP_D/128)*MAX_TILES), dim3(256), 0, stream>>>(
        Xg, W1, nullptr, b1, Hb, tileE, meta, slot_w);
    moe_gemm<EXP_D, D_MODEL, true, false><<<dim3((D_MODEL/128)*MAX_TILES), dim3(256), 0, stream>>>(
        Hb, W2, nullptr, b2, Yb, tileE, meta, slot_w);
  }
  combine_kernel<<<dim3(NTOK), dim3(256), 0, stream>>>(Yb, tok_slot, out);
}